// Round 4
// baseline (129.034 us; speedup 1.0000x reference)
//
#include <hip/hip_runtime.h>

// FirstBlockTexture — full-MFMA facet pipeline (32 facets/wave) + CSR gather.
// facet_kernel: per wave 2 sub-tiles of 16 facets; all GEMMs on
//   mfma_f32_16x16x32_bf16; inputs LDS-staged cooperatively (float4);
//   weight B-frags shared across both sub-tiles (halves L2 frag traffic);
//   y[NF,64] written bf16 via LDS transpose (coalesced dwordx4).
// scanA/B/C: exclusive prefix-scan of full_nf_count -> CSR row starts.
// vertex_kernel: wave per vertex, lane=channel; gathers bf16 y rows via
//   vt_map, mean + b_pw + relu fused.

typedef float f32x4 __attribute__((ext_vector_type(4)));
typedef short s16x8 __attribute__((ext_vector_type(8)));
typedef unsigned int u32;

__device__ __forceinline__ short f2bf(float x) {
    union { float f; u32 u; } v; v.f = x;
    u32 r = (v.u + 0x7fffu + ((v.u >> 16) & 1u)) >> 16;   // RNE
    return (short)r;
}
__device__ __forceinline__ float bf2f_(unsigned short u) {
    union { u32 u; float f; } x; x.u = ((u32)u) << 16; return x.f;
}
__device__ __forceinline__ u32 pkh(float a, float b) {
    union { _Float16 h[2]; u32 u; } x; x.h[0] = (_Float16)a; x.h[1] = (_Float16)b; return x.u;
}
__device__ __forceinline__ float uph(u32 w, int hi) {
    union { u32 u; _Float16 h[2]; } x; x.u = w; return (float)x.h[hi];
}

// ws frag table: 56 segments * 64 lanes * 16B = 57344 B
__global__ void prep_kernel(const float* __restrict__ Wf2f, const float* __restrict__ Wmlp,
                            const float* __restrict__ Wdw,  const float* __restrict__ Wpw,
                            s16x8* __restrict__ wsAll)
{
    int gid = blockIdx.x * 256 + threadIdx.x;
    if (gid >= 56 * 64) return;
    int l = gid & 63, seg = gid >> 6;
    int k4 = l >> 4, o = l & 15;
    s16x8 v;
    if (seg < 4) {
#pragma unroll
        for (int j = 0; j < 8; ++j) { int k = k4 * 8 + j; v[j] = (k < 9) ? f2bf(Wf2f[k * 64 + seg * 16 + o]) : (short)0; }
    } else if (seg < 8) {
        int nt = seg - 4;
#pragma unroll
        for (int j = 0; j < 8; ++j) { int k = k4 * 8 + j; v[j] = (k < 8) ? f2bf(Wmlp[k * 64 + nt * 16 + o]) : (short)0; }
    } else if (seg < 24) {
        int nt2 = seg - 8;
#pragma unroll
        for (int j = 0; j < 8; ++j) { int k = k4 * 8 + j; v[j] = (k < 27) ? f2bf(Wdw[k * 256 + nt2 * 16 + o]) : (short)0; }
    } else {
        int s = seg - 24, nt = s >> 3, kc = s & 7;
#pragma unroll
        for (int j = 0; j < 8; ++j) { int k = kc * 32 + k4 * 8 + j; v[j] = f2bf(Wpw[k * 64 + nt * 16 + o]); }
    }
    wsAll[gid] = v;
}

// ---------------- prefix scan of nf_count ----------------
__global__ void scanA(const int* __restrict__ nfc, int* __restrict__ bsum, int NV)
{
    __shared__ int sd[256];
    int b = blockIdx.x, t = threadIdx.x;
    int v0 = b * 512 + 2 * t;
    int e0 = (v0 < NV) ? nfc[v0] : 0;
    int e1 = (v0 + 1 < NV) ? nfc[v0 + 1] : 0;
    sd[t] = e0 + e1;
    __syncthreads();
    for (int off = 128; off > 0; off >>= 1) {
        if (t < off) sd[t] += sd[t + off];
        __syncthreads();
    }
    if (t == 0) bsum[b] = sd[0];
}

__global__ void scanB(const int* __restrict__ bsum, int* __restrict__ boff, int NB)
{
    __shared__ int sd[256];
    int t = threadIdx.x;
    int s = (t < NB) ? bsum[t] : 0;
    sd[t] = s;
    __syncthreads();
    for (int off = 1; off < 256; off <<= 1) {
        int v = (t >= off) ? sd[t - off] : 0;
        __syncthreads();
        sd[t] += v;
        __syncthreads();
    }
    if (t < NB) boff[t] = sd[t] - s;   // exclusive
}

__global__ void scanC(const int* __restrict__ nfc, const int* __restrict__ boff,
                      int* __restrict__ startArr, int NV)
{
    __shared__ int sd[256];
    int b = blockIdx.x, t = threadIdx.x;
    int v0 = b * 512 + 2 * t;
    int e0 = (v0 < NV) ? nfc[v0] : 0;
    int e1 = (v0 + 1 < NV) ? nfc[v0 + 1] : 0;
    int s = e0 + e1;
    sd[t] = s;
    __syncthreads();
    for (int off = 1; off < 256; off <<= 1) {
        int v = (t >= off) ? sd[t - off] : 0;
        __syncthreads();
        sd[t] += v;
        __syncthreads();
    }
    int off0 = boff[b] + sd[t] - s;
    if (v0 < NV) startArr[v0] = off0;
    if (v0 + 1 < NV) startArr[v0 + 1] = off0 + e0;
}

// ---------------- facet pipeline: 32 facets per wave ----------------
// Per-wave LDS slice (8 KB), used in 3 sequential phases (wave-private,
// in-order DS pipe -> no barriers):
//   1) input staging: 432 float4 = 6912 B
//      floats [0,288) bary(i*9+j) | [288,576) tex | [576,832) geo(i*8+g)
//             [832,1696) filt(i*27+k) | ints [1696,1728) numtex
//   2) ct k-phase buffer: [32 rows][128 k] bf16 = 8192 B, XOR-swizzled
//   3) y transpose tile: [32][64] bf16 = 4096 B, XOR-swizzled
__global__ __launch_bounds__(256, 4) void facet_kernel(
    const float* __restrict__ geo, const float* __restrict__ tex,
    const float* __restrict__ bary, const int* __restrict__ numtex,
    const float* __restrict__ filt,
    const float* __restrict__ bf2f, const float* __restrict__ bmlp,
    const s16x8* __restrict__ wsAll, unsigned short* __restrict__ ybf,
    int NF, int npairs)
{
    __shared__ char sAll[4][8192];
    const int l   = threadIdx.x & 63;
    const int wid = threadIdx.x >> 6;
    const int pair = blockIdx.x * 4 + wid;
    if (pair >= npairs) return;
    const int f0 = pair * 32;
    const int o16 = l & 15, k4 = l >> 4;
    char*  sW  = sAll[wid];
    float* sIn = (float*)sW;

    // ---- stage inputs (coalesced float4) ----
    if (f0 + 32 <= NF) {
        const float4* b4 = (const float4*)bary + 72 * (size_t)pair;
        const float4* t4 = (const float4*)tex  + 72 * (size_t)pair;
        const float4* g4 = (const float4*)geo  + 64 * (size_t)pair;
        const float4* q4 = (const float4*)filt + 216 * (size_t)pair;
        const float4* n4 = (const float4*)numtex + 8 * (size_t)pair;  // bit-exact copy
        float4* d4 = (float4*)sIn;
#pragma unroll
        for (int r = 0; r < 7; ++r) {
            int idx = l + r * 64;
            if (idx < 432) {
                float4 v;
                if      (idx < 72)  v = b4[idx];
                else if (idx < 144) v = t4[idx - 72];
                else if (idx < 208) v = g4[idx - 144];
                else if (idx < 424) v = q4[idx - 208];
                else                v = n4[idx - 424];
                d4[idx] = v;
            }
        }
    } else {
        for (int idx = l; idx < 1728; idx += 64) {
            if (idx < 288)       { int i = idx / 9, j = idx % 9;            int f = min(f0 + i, NF - 1); sIn[idx] = bary[9 * (size_t)f + j]; }
            else if (idx < 576)  { int e = idx - 288; int i = e / 9,  j = e % 9;  int f = min(f0 + i, NF - 1); sIn[idx] = tex [9 * (size_t)f + j]; }
            else if (idx < 832)  { int e = idx - 576; int i = e / 8,  g = e % 8;  int f = min(f0 + i, NF - 1); sIn[idx] = geo [8 * (size_t)f + g]; }
            else if (idx < 1696) { int e = idx - 832; int i = e / 27, k = e % 27; int f = min(f0 + i, NF - 1); sIn[idx] = filt[27 * (size_t)f + k]; }
            else                 { int i = idx - 1696;                            int f = min(f0 + i, NF - 1); ((int*)sIn)[idx] = numtex[f]; }
        }
    }

    const s16x8* wsF2f = wsAll;
    const s16x8* wsMlp = wsAll + 4 * 64;
    const s16x8* wsWdw = wsAll + 8 * 64;
    const s16x8* wsWpw = wsAll + 24 * 64;
    const f32x4 z4 = {0.f, 0.f, 0.f, 0.f};

    float bfo[4], bmo[4];
#pragma unroll
    for (int nt = 0; nt < 4; ++nt) { bfo[nt] = bf2f[nt * 16 + o16]; bmo[nt] = bmlp[nt * 16 + o16]; }

    // ---- front end per sub-tile: Tnet/Gnet packed f16x2, filt A-frags ----
    u32 tnp[2][4][2], gnp[2][4][2];    // [s][nt][t-pair]
    s16x8 aFlt[2];
#pragma unroll
    for (int s = 0; s < 2; ++s) {
        const int i = s * 16 + o16;
        const float* bp = sIn + i * 9;
        const float* tp = sIn + 288 + i * 9;
        float Bm[9] = {0.f,0.f,0.f,0.f,0.f,0.f,0.f,0.f,0.f};
#pragma unroll
        for (int t = 0; t < 3; ++t) {
            float b0 = bp[3*t], b1 = bp[3*t+1], b2 = bp[3*t+2];
            float x0 = tp[3*t], x1 = tp[3*t+1], x2 = tp[3*t+2];
            Bm[0] = fmaf(b0, x0, Bm[0]); Bm[1] = fmaf(b0, x1, Bm[1]); Bm[2] = fmaf(b0, x2, Bm[2]);
            Bm[3] = fmaf(b1, x0, Bm[3]); Bm[4] = fmaf(b1, x1, Bm[4]); Bm[5] = fmaf(b1, x2, Bm[5]);
            Bm[6] = fmaf(b2, x0, Bm[6]); Bm[7] = fmaf(b2, x1, Bm[7]); Bm[8] = fmaf(b2, x2, Bm[8]);
        }
        s16x8 aF2f;
        aF2f[0] = f2bf((k4 == 1) ? Bm[8] : Bm[0]);   // k4==1 supplies A[k=8]
#pragma unroll
        for (int j = 1; j < 8; ++j) aF2f[j] = f2bf(Bm[j]);

        const float* gp = sIn + 576 + i * 8;
        s16x8 aMlp;
#pragma unroll
        for (int j = 0; j < 8; ++j) aMlp[j] = f2bf(gp[j]);

        const float* fp = sIn + 832 + i * 27 + k4 * 8;
#pragma unroll
        for (int j = 0; j < 8; ++j) {
            int k = k4 * 8 + j;
            aFlt[s][j] = (k < 27) ? f2bf(fp[j]) : (short)0;
        }

        const int base = s * 16 + 4 * k4;
        float invn[4];
#pragma unroll
        for (int t = 0; t < 4; ++t) invn[t] = 1.0f / (float)((const int*)sIn)[1696 + base + t];

#pragma unroll
        for (int nt = 0; nt < 4; ++nt) {
            f32x4 aT = __builtin_amdgcn_mfma_f32_16x16x32_bf16(aF2f, wsF2f[nt * 64 + l], z4, 0, 0, 0);
            f32x4 aG = __builtin_amdgcn_mfma_f32_16x16x32_bf16(aMlp, wsMlp[nt * 64 + l], z4, 0, 0, 0);
            float tv[4], gv[4];
#pragma unroll
            for (int t = 0; t < 4; ++t) {
                bool mv = (f0 + base + t) < NF;
                tv[t] = mv ? fmaxf(fmaf(aT[t], invn[t], bfo[nt]), 0.f) : 0.f;
                gv[t] = mv ? fmaxf(aG[t] + bmo[nt], 0.f) : 0.f;
            }
            tnp[s][nt][0] = pkh(tv[0], tv[1]); tnp[s][nt][1] = pkh(tv[2], tv[3]);
            gnp[s][nt][0] = pkh(gv[0], gv[1]); gnp[s][nt][1] = pkh(gv[2], gv[3]);
        }
    }

    // ---- GEMM1 (ct) + GEMM2 (y), k-phase split, B-frags shared across sub-tiles ----
    f32x4 acc2[2][4] = {{z4, z4, z4, z4}, {z4, z4, z4, z4}};
#pragma unroll
    for (int p = 0; p < 2; ++p) {
#pragma unroll
        for (int s = 0; s < 2; ++s) {
#pragma unroll
            for (int nt2h = 0; nt2h < 8; ++nt2h) {
                const int nt2 = p * 8 + nt2h;
                f32x4 acc = __builtin_amdgcn_mfma_f32_16x16x32_bf16(aFlt[s], wsWdw[nt2 * 64 + l], z4, 0, 0, 0);
                const int srcl = k4 * 16 + (nt2 & 1) * 8 + (o16 >> 1);
                const int r = nt2h * 16 + o16;           // column within k-phase [0,128)
#pragma unroll
                for (int t = 0; t < 4; ++t) {
                    u32 w = (p == 0) ? __shfl(tnp[s][nt2h >> 1][t >> 1], srcl, 64)
                                     : __shfl(gnp[s][nt2h >> 1][t >> 1], srcl, 64);
                    float netv = uph(w, t & 1);
                    const int m = s * 16 + 4 * k4 + t;
                    *(short*)(sW + m * 256 + ((r * 2) ^ ((m & 7) << 4))) = f2bf(acc[t] * netv);
                }
            }
        }
#pragma unroll
        for (int kcl = 0; kcl < 4; ++kcl) {
            s16x8 a2[2];
#pragma unroll
            for (int s = 0; s < 2; ++s)
                a2[s] = *(const s16x8*)(sW + (s * 16 + o16) * 256 + ((kcl * 64 + k4 * 16) ^ ((o16 & 7) << 4)));
#pragma unroll
            for (int nt = 0; nt < 4; ++nt) {
                s16x8 frag = wsWpw[(nt * 8 + p * 4 + kcl) * 64 + l];
                acc2[0][nt] = __builtin_amdgcn_mfma_f32_16x16x32_bf16(a2[0], frag, acc2[0][nt], 0, 0, 0);
                acc2[1][nt] = __builtin_amdgcn_mfma_f32_16x16x32_bf16(a2[1], frag, acc2[1][nt], 0, 0, 0);
            }
        }
    }

    // ---- y -> bf16, LDS transpose, coalesced dwordx4 global stores ----
#pragma unroll
    for (int s = 0; s < 2; ++s)
#pragma unroll
        for (int nt = 0; nt < 4; ++nt)
#pragma unroll
            for (int t = 0; t < 4; ++t) {
                const int m = s * 16 + 4 * k4 + t;
                const int c = nt * 16 + o16;
                int off = m * 128 + c * 2;
                off ^= ((m & 7) << 4);
                *(short*)(sW + off) = f2bf(acc2[s][nt][t]);
            }
    unsigned short* dst = ybf + (size_t)pair * 2048;     // [32][64] bf16
    {
        const int m = l >> 1;
#pragma unroll
        for (int q = 0; q < 4; ++q) {
            const int L = l * 64 + q * 16;
            s16x8 v = *(const s16x8*)(sW + (L ^ ((m & 7) << 4)));
            *(s16x8*)((char*)dst + L) = v;
        }
    }
}

// ---------------- CSR gather: mean + bias + relu ----------------
__global__ __launch_bounds__(256) void vertex_kernel(
    const unsigned short* __restrict__ ybf, const int* __restrict__ vt_map,
    const int* __restrict__ startArr, const int* __restrict__ nfc,
    const float* __restrict__ bpw, float* __restrict__ out, int NV)
{
    const int wid  = threadIdx.x >> 6;
    const int lane = threadIdx.x & 63;
    const int v = blockIdx.x * 4 + wid;
    if (v >= NV) return;
    const int start = startArr[v];
    const int cnt   = nfc[v];
    float acc = 0.f;
    int i = 0;
    for (; i + 4 <= cnt; i += 4) {
        const int fa = vt_map[start + i];
        const int fb = vt_map[start + i + 1];
        const int fc = vt_map[start + i + 2];
        const int fd = vt_map[start + i + 3];
        float a = bf2f_(ybf[(size_t)fa * 64 + lane]);
        float b = bf2f_(ybf[(size_t)fb * 64 + lane]);
        float c = bf2f_(ybf[(size_t)fc * 64 + lane]);
        float d = bf2f_(ybf[(size_t)fd * 64 + lane]);
        acc += (a + b) + (c + d);
    }
    for (; i < cnt; ++i) acc += bf2f_(ybf[(size_t)vt_map[start + i] * 64 + lane]);
    const float inv = 1.0f / (float)(cnt > 0 ? cnt : 1);
    out[(size_t)v * 64 + lane] = fmaxf(fmaf(acc, inv, bpw[lane]), 0.f);
}

extern "C" void kernel_launch(void* const* d_in, const int* in_sizes, int n_in,
                              void* d_out, int out_size, void* d_ws, size_t ws_size,
                              hipStream_t stream)
{
    const float* geo    = (const float*)d_in[0];   // [NF,8]
    const float* tex    = (const float*)d_in[1];   // [T,3]
    const float* bary   = (const float*)d_in[2];   // [T,3]
    const int*   numtex = (const int*)  d_in[3];   // [NF]
    const int*   nfc    = (const int*)  d_in[5];   // [NV]
    const int*   vtmap  = (const int*)  d_in[6];   // [3*NF]
    const float* filt   = (const float*)d_in[7];   // [NF,27]
    const float* Wf2f   = (const float*)d_in[8];   // [9,64]
    const float* bf2f   = (const float*)d_in[9];   // [64]
    const float* Wmlp   = (const float*)d_in[10];  // [8,64]
    const float* bmlp   = (const float*)d_in[11];  // [64]
    const float* Wdw    = (const float*)d_in[12];  // [27,128,2]
    const float* Wpw    = (const float*)d_in[13];  // [256,64]
    const float* bpw    = (const float*)d_in[14];  // [64]
    float* out = (float*)d_out;

    const int NF = in_sizes[0] / 8;
    const int NV = in_sizes[5];
    const int npairs = (NF + 31) / 32;
    const int NB = (NV + 511) / 512;               // <=256 for NV<=131072

    // ws layout
    const size_t offFrag  = 0;                                   // 57344 B
    const size_t offY     = 57344;                               // npairs*4096 B (bf16 y)
    const size_t offStart = offY + (size_t)npairs * 4096;
    const size_t offBsum  = offStart + (((size_t)NV * 4 + 255) & ~(size_t)255);
    const size_t offBoff  = offBsum + 1024;

    s16x8*          wsAll    = (s16x8*)((char*)d_ws + offFrag);
    unsigned short* ybf      = (unsigned short*)((char*)d_ws + offY);
    int*            startArr = (int*)((char*)d_ws + offStart);
    int*            bsum     = (int*)((char*)d_ws + offBsum);
    int*            boff     = (int*)((char*)d_ws + offBoff);

    hipLaunchKernelGGL(prep_kernel, dim3(14), dim3(256), 0, stream,
                       Wf2f, Wmlp, Wdw, Wpw, wsAll);
    hipLaunchKernelGGL(scanA, dim3(NB), dim3(256), 0, stream, nfc, bsum, NV);
    hipLaunchKernelGGL(scanB, dim3(1),  dim3(256), 0, stream, bsum, boff, NB);
    hipLaunchKernelGGL(scanC, dim3(NB), dim3(256), 0, stream, nfc, boff, startArr, NV);

    hipLaunchKernelGGL(facet_kernel, dim3((npairs + 3) / 4), dim3(256), 0, stream,
                       geo, tex, bary, numtex, filt, bf2f, bmlp, wsAll, ybf, NF, npairs);

    hipLaunchKernelGGL(vertex_kernel, dim3((NV + 3) / 4), dim3(256), 0, stream,
                       ybf, vtmap, startArr, nfc, bpw, out, NV);
}

// Round 5
// 80.901 us; speedup vs baseline: 1.5950x; 1.5950x over previous
//
#include <hip/hip_runtime.h>

// FirstBlockTexture — full-MFMA facet pipeline (16 facets/wave, round-3
// structure) + CSR gather. Changes vs round 3:
//   - per-wave inputs LDS-staged with coalesced float4 (replaces 34 scattered
//     scalar loads/lane); same 8 KB wave slice is reused in 3 sequential
//     wave-private phases: inputs -> ct tile -> y transpose (in-order DS pipe,
//     no barriers needed).
//   - y written bf16 via LDS transpose (write 50->12.8 MB; vertex gather halves).
// Round-4 lesson: 32 facets/wave doubled live state -> scratch spills
// (WRITE 130 MB). Keep live state at round-3's 64-VGPR footprint.

typedef float f32x4 __attribute__((ext_vector_type(4)));
typedef short s16x8 __attribute__((ext_vector_type(8)));
typedef unsigned int u32;

__device__ __forceinline__ short f2bf(float x) {
    union { float f; u32 u; } v; v.f = x;
    u32 r = (v.u + 0x7fffu + ((v.u >> 16) & 1u)) >> 16;   // RNE
    return (short)r;
}

// ws frag table: 56 segments * 64 lanes * 16B = 57344 B
__global__ void prep_kernel(const float* __restrict__ Wf2f, const float* __restrict__ Wmlp,
                            const float* __restrict__ Wdw,  const float* __restrict__ Wpw,
                            s16x8* __restrict__ wsAll)
{
    int gid = blockIdx.x * 256 + threadIdx.x;
    if (gid >= 56 * 64) return;
    int l = gid & 63, seg = gid >> 6;
    int k4 = l >> 4, o = l & 15;
    s16x8 v;
    if (seg < 4) {
#pragma unroll
        for (int j = 0; j < 8; ++j) { int k = k4 * 8 + j; v[j] = (k < 9) ? f2bf(Wf2f[k * 64 + seg * 16 + o]) : (short)0; }
    } else if (seg < 8) {
        int nt = seg - 4;
#pragma unroll
        for (int j = 0; j < 8; ++j) { int k = k4 * 8 + j; v[j] = (k < 8) ? f2bf(Wmlp[k * 64 + nt * 16 + o]) : (short)0; }
    } else if (seg < 24) {
        int nt2 = seg - 8;
#pragma unroll
        for (int j = 0; j < 8; ++j) { int k = k4 * 8 + j; v[j] = (k < 27) ? f2bf(Wdw[k * 256 + nt2 * 16 + o]) : (short)0; }
    } else {
        int s = seg - 24, nt = s >> 3, kc = s & 7;
#pragma unroll
        for (int j = 0; j < 8; ++j) { int k = kc * 32 + k4 * 8 + j; v[j] = f2bf(Wpw[k * 64 + nt * 16 + o]); }
    }
    wsAll[gid] = v;
}

// ---------------- prefix scan of nf_count ----------------
__global__ void scanA(const int* __restrict__ nfc, int* __restrict__ bsum, int NV)
{
    __shared__ int sd[256];
    int b = blockIdx.x, t = threadIdx.x;
    int v0 = b * 512 + 2 * t;
    int e0 = (v0 < NV) ? nfc[v0] : 0;
    int e1 = (v0 + 1 < NV) ? nfc[v0 + 1] : 0;
    sd[t] = e0 + e1;
    __syncthreads();
    for (int off = 128; off > 0; off >>= 1) {
        if (t < off) sd[t] += sd[t + off];
        __syncthreads();
    }
    if (t == 0) bsum[b] = sd[0];
}

__global__ void scanB(const int* __restrict__ bsum, int* __restrict__ boff, int NB)
{
    __shared__ int sd[256];
    int t = threadIdx.x;
    int s = (t < NB) ? bsum[t] : 0;
    sd[t] = s;
    __syncthreads();
    for (int off = 1; off < 256; off <<= 1) {
        int v = (t >= off) ? sd[t - off] : 0;
        __syncthreads();
        sd[t] += v;
        __syncthreads();
    }
    if (t < NB) boff[t] = sd[t] - s;   // exclusive
}

__global__ void scanC(const int* __restrict__ nfc, const int* __restrict__ boff,
                      int* __restrict__ startArr, int NV)
{
    __shared__ int sd[256];
    int b = blockIdx.x, t = threadIdx.x;
    int v0 = b * 512 + 2 * t;
    int e0 = (v0 < NV) ? nfc[v0] : 0;
    int e1 = (v0 + 1 < NV) ? nfc[v0 + 1] : 0;
    int s = e0 + e1;
    sd[t] = s;
    __syncthreads();
    for (int off = 1; off < 256; off <<= 1) {
        int v = (t >= off) ? sd[t - off] : 0;
        __syncthreads();
        sd[t] += v;
        __syncthreads();
    }
    int off0 = boff[b] + sd[t] - s;
    if (v0 < NV) startArr[v0] = off0;
    if (v0 + 1 < NV) startArr[v0 + 1] = off0 + e0;
}

// ---------------- facet pipeline: 16 facets per wave ----------------
// Per-wave 8 KB LDS slice, 3 sequential wave-private phases:
//   1) inputs: floats [0,144) bary | [144,288) tex | [288,416) geo
//              [416,848) filt | ints [848,864) numtex      (3456 B)
//   2) ct tile [16][256] bf16, XOR-swizzled                 (8192 B)
//   3) y tile  [16][64]  bf16, XOR-swizzled                 (2048 B)
__global__ __launch_bounds__(256, 4) void facet_kernel(
    const float* __restrict__ geo, const float* __restrict__ tex,
    const float* __restrict__ bary, const int* __restrict__ numtex,
    const float* __restrict__ filt,
    const float* __restrict__ bf2f, const float* __restrict__ bmlp,
    const s16x8* __restrict__ wsAll, unsigned short* __restrict__ ybf,
    int NF, int ntiles)
{
    __shared__ char sAll[4][8192];
    const int l   = threadIdx.x & 63;
    const int wid = threadIdx.x >> 6;
    const int tile = blockIdx.x * 4 + wid;
    if (tile >= ntiles) return;
    const int f0 = tile * 16;
    const int o16 = l & 15, k4 = l >> 4;
    char*  sW  = sAll[wid];
    float* sIn = (float*)sW;

    // ---- phase 1: stage inputs (coalesced float4) ----
    if (f0 + 16 <= NF) {
        const float4* b4 = (const float4*)bary + 36 * (size_t)tile;
        const float4* t4 = (const float4*)tex  + 36 * (size_t)tile;
        const float4* g4 = (const float4*)geo  + 32 * (size_t)tile;
        const float4* q4 = (const float4*)filt + 108 * (size_t)tile;
        const float4* n4 = (const float4*)numtex + 4 * (size_t)tile;  // bit-exact int copy
        float4* d4 = (float4*)sIn;
#pragma unroll
        for (int r = 0; r < 4; ++r) {
            int idx = l + r * 64;
            if (idx < 216) {
                float4 v;
                if      (idx < 36)  v = b4[idx];
                else if (idx < 72)  v = t4[idx - 36];
                else if (idx < 104) v = g4[idx - 72];
                else if (idx < 212) v = q4[idx - 104];
                else                v = n4[idx - 212];
                d4[idx] = v;
            }
        }
    } else {
        for (int idx = l; idx < 864; idx += 64) {
            if (idx < 144)       { int i = idx / 9, j = idx % 9;              int f = min(f0 + i, NF - 1); sIn[idx] = bary[9 * (size_t)f + j]; }
            else if (idx < 288)  { int e = idx - 144; int i = e / 9,  j = e % 9;  int f = min(f0 + i, NF - 1); sIn[idx] = tex [9 * (size_t)f + j]; }
            else if (idx < 416)  { int e = idx - 288; int i = e / 8,  g = e % 8;  int f = min(f0 + i, NF - 1); sIn[idx] = geo [8 * (size_t)f + g]; }
            else if (idx < 848)  { int e = idx - 416; int i = e / 27, k = e % 27; int f = min(f0 + i, NF - 1); sIn[idx] = filt[27 * (size_t)f + k]; }
            else                 { int i = idx - 848;                              int f = min(f0 + i, NF - 1); ((int*)sIn)[idx] = numtex[f]; }
        }
    }

    const s16x8* wsF2f = wsAll;
    const s16x8* wsMlp = wsAll + 4 * 64;
    const s16x8* wsWdw = wsAll + 8 * 64;
    const s16x8* wsWpw = wsAll + 24 * 64;
    const f32x4 z4 = {0.f, 0.f, 0.f, 0.f};

    // ---- front end: A-frags + Tnet/Gnet from LDS inputs ----
    const int i = o16;
    const float* bp = sIn + i * 9;
    const float* tp = sIn + 144 + i * 9;
    float Bm[9] = {0.f,0.f,0.f,0.f,0.f,0.f,0.f,0.f,0.f};
#pragma unroll
    for (int t = 0; t < 3; ++t) {
        float b0 = bp[3*t], b1 = bp[3*t+1], b2 = bp[3*t+2];
        float x0 = tp[3*t], x1 = tp[3*t+1], x2 = tp[3*t+2];
        Bm[0] = fmaf(b0, x0, Bm[0]); Bm[1] = fmaf(b0, x1, Bm[1]); Bm[2] = fmaf(b0, x2, Bm[2]);
        Bm[3] = fmaf(b1, x0, Bm[3]); Bm[4] = fmaf(b1, x1, Bm[4]); Bm[5] = fmaf(b1, x2, Bm[5]);
        Bm[6] = fmaf(b2, x0, Bm[6]); Bm[7] = fmaf(b2, x1, Bm[7]); Bm[8] = fmaf(b2, x2, Bm[8]);
    }
    s16x8 aF2f;
    aF2f[0] = f2bf((k4 == 1) ? Bm[8] : Bm[0]);   // k4==1 lane supplies A[k=8]
#pragma unroll
    for (int j = 1; j < 8; ++j) aF2f[j] = f2bf(Bm[j]);

    const float* gp = sIn + 288 + i * 8;
    s16x8 aMlp;
#pragma unroll
    for (int j = 0; j < 8; ++j) aMlp[j] = f2bf(gp[j]);

    const float* fp = sIn + 416 + i * 27 + k4 * 8;
    s16x8 aFlt;
#pragma unroll
    for (int j = 0; j < 8; ++j) {
        int k = k4 * 8 + j;
        aFlt[j] = (k < 27) ? f2bf(fp[j]) : (short)0;
    }

    float invn[4];
#pragma unroll
    for (int t = 0; t < 4; ++t) invn[t] = 1.0f / (float)((const int*)sIn)[848 + 4 * k4 + t];
    float bfo[4], bmo[4];
#pragma unroll
    for (int nt = 0; nt < 4; ++nt) { bfo[nt] = bf2f[nt * 16 + o16]; bmo[nt] = bmlp[nt * 16 + o16]; }

    float tn[4][4], gn[4][4];                // [nt][t], D-layout row m=4*k4+t, col nt*16+o16
#pragma unroll
    for (int nt = 0; nt < 4; ++nt) {
        f32x4 aT = __builtin_amdgcn_mfma_f32_16x16x32_bf16(aF2f, wsF2f[nt * 64 + l], z4, 0, 0, 0);
        f32x4 aG = __builtin_amdgcn_mfma_f32_16x16x32_bf16(aMlp, wsMlp[nt * 64 + l], z4, 0, 0, 0);
#pragma unroll
        for (int t = 0; t < 4; ++t) {
            bool mv = (f0 + 4 * k4 + t) < NF;
            float tv = fmaxf(fmaf(aT[t], invn[t], bfo[nt]), 0.f);
            float gv = fmaxf(aG[t] + bmo[nt], 0.f);
            tn[nt][t] = mv ? tv : 0.f;
            gn[nt][t] = mv ? gv : 0.f;
        }
    }

    // ---- phase 2 / GEMM1: mk = filt16 @ Wdw ; ct = mk * net -> sW (bf16, swizzled) ----
#pragma unroll
    for (int nt2 = 0; nt2 < 16; ++nt2) {
        f32x4 acc = __builtin_amdgcn_mfma_f32_16x16x32_bf16(aFlt, wsWdw[nt2 * 64 + l], z4, 0, 0, 0);
        const int srcl = k4 * 16 + (nt2 & 1) * 8 + (o16 >> 1);
        const int r = nt2 * 16 + o16;
#pragma unroll
        for (int t = 0; t < 4; ++t) {
            float netv = (nt2 < 8) ? __shfl(tn[nt2 >> 1][t], srcl, 64)
                                   : __shfl(gn[(nt2 - 8) >> 1][t], srcl, 64);
            float cv = acc[t] * netv;
            const int m = 4 * k4 + t;
            *(short*)(sW + m * 512 + ((r * 2) ^ ((m & 7) << 4))) = f2bf(cv);
        }
    }

    // ---- GEMM2: y = ct @ Wpw ----
    f32x4 acc2[4] = {z4, z4, z4, z4};
#pragma unroll
    for (int kc = 0; kc < 8; ++kc) {
        s16x8 a2 = *(const s16x8*)(sW + o16 * 512 + ((kc * 64 + k4 * 16) ^ ((o16 & 7) << 4)));
#pragma unroll
        for (int nt = 0; nt < 4; ++nt)
            acc2[nt] = __builtin_amdgcn_mfma_f32_16x16x32_bf16(a2, wsWpw[(nt * 8 + kc) * 64 + l], acc2[nt], 0, 0, 0);
    }

    // ---- phase 3: y -> bf16 via LDS transpose, coalesced dwordx4 stores ----
#pragma unroll
    for (int nt = 0; nt < 4; ++nt)
#pragma unroll
        for (int t = 0; t < 4; ++t) {
            const int m = 4 * k4 + t;
            const int c = nt * 16 + o16;
            int off = m * 128 + c * 2;
            off ^= ((m & 7) << 4);
            *(short*)(sW + off) = f2bf(acc2[nt][t]);
        }
    {
        char* dst = (char*)(ybf) + (size_t)tile * 2048;   // [16][64] bf16
#pragma unroll
        for (int q = 0; q < 2; ++q) {
            const int L = (l + q * 64) * 16;
            const int m = L >> 7;
            s16x8 v = *(const s16x8*)(sW + (L ^ ((m & 7) << 4)));
            *(s16x8*)(dst + L) = v;
        }
    }
}

// ---------------- CSR gather: mean + bias + relu ----------------
// thread = (vertex, channel-pair); one u32 (2 bf16) per incidence.
__global__ __launch_bounds__(256) void vertex_kernel(
    const u32* __restrict__ y32, const int* __restrict__ vt_map,
    const int* __restrict__ startArr, const int* __restrict__ nfc,
    const float* __restrict__ bpw, float* __restrict__ out, int NV)
{
    const int tid = blockIdx.x * 256 + threadIdx.x;
    const int v  = tid >> 5;
    const int c2 = tid & 31;
    if (v >= NV) return;
    const int start = startArr[v];
    const int cnt   = nfc[v];
    float aLo = 0.f, aHi = 0.f;
    int i = 0;
    for (; i + 4 <= cnt; i += 4) {
        const int fa = vt_map[start + i];
        const int fb = vt_map[start + i + 1];
        const int fc = vt_map[start + i + 2];
        const int fd = vt_map[start + i + 3];
        u32 wa = y32[(size_t)fa * 32 + c2];
        u32 wb = y32[(size_t)fb * 32 + c2];
        u32 wc = y32[(size_t)fc * 32 + c2];
        u32 wd = y32[(size_t)fd * 32 + c2];
        union { u32 u; float f; } x;
        x.u = wa << 16; aLo += x.f;  x.u = wa & 0xffff0000u; aHi += x.f;
        x.u = wb << 16; aLo += x.f;  x.u = wb & 0xffff0000u; aHi += x.f;
        x.u = wc << 16; aLo += x.f;  x.u = wc & 0xffff0000u; aHi += x.f;
        x.u = wd << 16; aLo += x.f;  x.u = wd & 0xffff0000u; aHi += x.f;
    }
    for (; i < cnt; ++i) {
        u32 w = y32[(size_t)vt_map[start + i] * 32 + c2];
        union { u32 u; float f; } x;
        x.u = w << 16; aLo += x.f;  x.u = w & 0xffff0000u; aHi += x.f;
    }
    const float inv = 1.0f / (float)(cnt > 0 ? cnt : 1);
    float2 r;
    r.x = fmaxf(fmaf(aLo, inv, bpw[2 * c2]), 0.f);
    r.y = fmaxf(fmaf(aHi, inv, bpw[2 * c2 + 1]), 0.f);
    *(float2*)(out + (size_t)v * 64 + 2 * c2) = r;
}

extern "C" void kernel_launch(void* const* d_in, const int* in_sizes, int n_in,
                              void* d_out, int out_size, void* d_ws, size_t ws_size,
                              hipStream_t stream)
{
    const float* geo    = (const float*)d_in[0];   // [NF,8]
    const float* tex    = (const float*)d_in[1];   // [T,3]
    const float* bary   = (const float*)d_in[2];   // [T,3]
    const int*   numtex = (const int*)  d_in[3];   // [NF]
    const int*   nfc    = (const int*)  d_in[5];   // [NV]
    const int*   vtmap  = (const int*)  d_in[6];   // [3*NF]
    const float* filt   = (const float*)d_in[7];   // [NF,27]
    const float* Wf2f   = (const float*)d_in[8];   // [9,64]
    const float* bf2f   = (const float*)d_in[9];   // [64]
    const float* Wmlp   = (const float*)d_in[10];  // [8,64]
    const float* bmlp   = (const float*)d_in[11];  // [64]
    const float* Wdw    = (const float*)d_in[12];  // [27,128,2]
    const float* Wpw    = (const float*)d_in[13];  // [256,64]
    const float* bpw    = (const float*)d_in[14];  // [64]
    float* out = (float*)d_out;

    const int NF = in_sizes[0] / 8;
    const int NV = in_sizes[5];
    const int ntiles = (NF + 15) / 16;
    const int NB = (NV + 511) / 512;               // <=256 for NV<=131072

    // ws layout
    const size_t offFrag  = 0;                                   // 57344 B
    const size_t offY     = 57344;                               // ntiles*2048 B (bf16 y)
    const size_t offStart = offY + (size_t)ntiles * 2048;
    const size_t offBsum  = offStart + (((size_t)NV * 4 + 255) & ~(size_t)255);
    const size_t offBoff  = offBsum + 1024;

    s16x8*          wsAll    = (s16x8*)((char*)d_ws + offFrag);
    unsigned short* ybf      = (unsigned short*)((char*)d_ws + offY);
    int*            startArr = (int*)((char*)d_ws + offStart);
    int*            bsum     = (int*)((char*)d_ws + offBsum);
    int*            boff     = (int*)((char*)d_ws + offBoff);

    hipLaunchKernelGGL(prep_kernel, dim3(14), dim3(256), 0, stream,
                       Wf2f, Wmlp, Wdw, Wpw, wsAll);
    hipLaunchKernelGGL(scanA, dim3(NB), dim3(256), 0, stream, nfc, bsum, NV);
    hipLaunchKernelGGL(scanB, dim3(1),  dim3(256), 0, stream, bsum, boff, NB);
    hipLaunchKernelGGL(scanC, dim3(NB), dim3(256), 0, stream, nfc, boff, startArr, NV);

    hipLaunchKernelGGL(facet_kernel, dim3((ntiles + 3) / 4), dim3(256), 0, stream,
                       geo, tex, bary, numtex, filt, bf2f, bmlp, wsAll, ybf, NF, ntiles);

    const int vthreads = NV * 32;
    hipLaunchKernelGGL(vertex_kernel, dim3((vthreads + 255) / 256), dim3(256), 0, stream,
                       (const u32*)ybf, vtmap, startArr, nfc, bpw, out, NV);
}

// Round 6
// 77.936 us; speedup vs baseline: 1.6556x; 1.0380x over previous
//
#include <hip/hip_runtime.h>

// FirstBlockTexture — full-MFMA facet pipeline (16 facets/wave) + CSR gather.
// Round-6 change: permute W_dw columns / W_pw rows at prep time so that the
// depthwise ⊙net multiply needs NO cross-lane shfl:
//   r' = (cblk*2+d)*16 + o16  <->  orig col 32*cblk + 2*o16 + d
// With this ordering, mk-D lane (k4,o16) tile nt2 needs net[4k4+t][(nt2>>1)*16+o16],
// which is the tn/gn register the SAME lane holds. (Was 64 ds_bpermute/tile.)
// GEMM2 consumes Wpw rows permuted identically -> same sum, fp reorder only.

typedef float f32x4 __attribute__((ext_vector_type(4)));
typedef short s16x8 __attribute__((ext_vector_type(8)));
typedef unsigned int u32;

__device__ __forceinline__ short f2bf(float x) {
    union { float f; u32 u; } v; v.f = x;
    u32 r = (v.u + 0x7fffu + ((v.u >> 16) & 1u)) >> 16;   // RNE
    return (short)r;
}

// ws frag table: 56 segments * 64 lanes * 16B = 57344 B
//   seg 0..3  : Wf2f B-frags (nt)       K=9  pad32
//   seg 4..7  : Wmlp B-frags (nt)       K=8  pad32
//   seg 8..23 : Wdw  B-frags (nt2), COLUMN-PERMUTED: col o16 <- 32*cblk+2*o16+d
//   seg 24..55: Wpw  B-frags (nt*8+kc), ROW-PERMUTED to match
__global__ void prep_kernel(const float* __restrict__ Wf2f, const float* __restrict__ Wmlp,
                            const float* __restrict__ Wdw,  const float* __restrict__ Wpw,
                            s16x8* __restrict__ wsAll)
{
    int gid = blockIdx.x * 256 + threadIdx.x;
    if (gid >= 56 * 64) return;
    int l = gid & 63, seg = gid >> 6;
    int k4 = l >> 4, o = l & 15;
    s16x8 v;
    if (seg < 4) {
#pragma unroll
        for (int j = 0; j < 8; ++j) { int k = k4 * 8 + j; v[j] = (k < 9) ? f2bf(Wf2f[k * 64 + seg * 16 + o]) : (short)0; }
    } else if (seg < 8) {
        int nt = seg - 4;
#pragma unroll
        for (int j = 0; j < 8; ++j) { int k = k4 * 8 + j; v[j] = (k < 8) ? f2bf(Wmlp[k * 64 + nt * 16 + o]) : (short)0; }
    } else if (seg < 24) {
        int nt2 = seg - 8;
        int cblk = nt2 >> 1, d = nt2 & 1;
        int col = 32 * cblk + 2 * o + d;          // permuted column
#pragma unroll
        for (int j = 0; j < 8; ++j) { int k = k4 * 8 + j; v[j] = (k < 27) ? f2bf(Wdw[k * 256 + col]) : (short)0; }
    } else {
        int s = seg - 24, nt = s >> 3, kc = s & 7;
#pragma unroll
        for (int j = 0; j < 8; ++j) {
            int rp = kc * 32 + k4 * 8 + j;        // permuted row index
            int nt2r = rp >> 4, orr = rp & 15;
            int orig = 32 * (nt2r >> 1) + 2 * orr + (nt2r & 1);
            v[j] = f2bf(Wpw[orig * 64 + nt * 16 + o]);
        }
    }
    wsAll[gid] = v;
}

// ---------------- prefix scan of nf_count ----------------
__global__ void scanA(const int* __restrict__ nfc, int* __restrict__ bsum, int NV)
{
    __shared__ int sd[256];
    int b = blockIdx.x, t = threadIdx.x;
    int v0 = b * 512 + 2 * t;
    int e0 = (v0 < NV) ? nfc[v0] : 0;
    int e1 = (v0 + 1 < NV) ? nfc[v0 + 1] : 0;
    sd[t] = e0 + e1;
    __syncthreads();
    for (int off = 128; off > 0; off >>= 1) {
        if (t < off) sd[t] += sd[t + off];
        __syncthreads();
    }
    if (t == 0) bsum[b] = sd[0];
}

__global__ void scanB(const int* __restrict__ bsum, int* __restrict__ boff, int NB)
{
    __shared__ int sd[256];
    int t = threadIdx.x;
    int s = (t < NB) ? bsum[t] : 0;
    sd[t] = s;
    __syncthreads();
    for (int off = 1; off < 256; off <<= 1) {
        int v = (t >= off) ? sd[t - off] : 0;
        __syncthreads();
        sd[t] += v;
        __syncthreads();
    }
    if (t < NB) boff[t] = sd[t] - s;   // exclusive
}

__global__ void scanC(const int* __restrict__ nfc, const int* __restrict__ boff,
                      int* __restrict__ startArr, int NV)
{
    __shared__ int sd[256];
    int b = blockIdx.x, t = threadIdx.x;
    int v0 = b * 512 + 2 * t;
    int e0 = (v0 < NV) ? nfc[v0] : 0;
    int e1 = (v0 + 1 < NV) ? nfc[v0 + 1] : 0;
    int s = e0 + e1;
    sd[t] = s;
    __syncthreads();
    for (int off = 1; off < 256; off <<= 1) {
        int v = (t >= off) ? sd[t - off] : 0;
        __syncthreads();
        sd[t] += v;
        __syncthreads();
    }
    int off0 = boff[b] + sd[t] - s;
    if (v0 < NV) startArr[v0] = off0;
    if (v0 + 1 < NV) startArr[v0 + 1] = off0 + e0;
}

// ---------------- facet pipeline: 16 facets per wave ----------------
// Per-wave 8 KB LDS slice, 3 sequential wave-private phases (no barriers):
//   1) inputs (3456 B) 2) ct tile [16][256] bf16 swizzled (8192 B)
//   3) y tile [16][64] bf16 swizzled (2048 B)
__global__ __launch_bounds__(256, 5) void facet_kernel(
    const float* __restrict__ geo, const float* __restrict__ tex,
    const float* __restrict__ bary, const int* __restrict__ numtex,
    const float* __restrict__ filt,
    const float* __restrict__ bf2f, const float* __restrict__ bmlp,
    const s16x8* __restrict__ wsAll, unsigned short* __restrict__ ybf,
    int NF, int ntiles)
{
    __shared__ char sAll[4][8192];
    const int l   = threadIdx.x & 63;
    const int wid = threadIdx.x >> 6;
    const int tile = blockIdx.x * 4 + wid;
    if (tile >= ntiles) return;
    const int f0 = tile * 16;
    const int o16 = l & 15, k4 = l >> 4;
    char*  sW  = sAll[wid];
    float* sIn = (float*)sW;

    // ---- phase 1: stage inputs (coalesced float4) ----
    if (f0 + 16 <= NF) {
        const float4* b4 = (const float4*)bary + 36 * (size_t)tile;
        const float4* t4 = (const float4*)tex  + 36 * (size_t)tile;
        const float4* g4 = (const float4*)geo  + 32 * (size_t)tile;
        const float4* q4 = (const float4*)filt + 108 * (size_t)tile;
        const float4* n4 = (const float4*)numtex + 4 * (size_t)tile;  // bit-exact int copy
        float4* d4 = (float4*)sIn;
#pragma unroll
        for (int r = 0; r < 4; ++r) {
            int idx = l + r * 64;
            if (idx < 216) {
                float4 v;
                if      (idx < 36)  v = b4[idx];
                else if (idx < 72)  v = t4[idx - 36];
                else if (idx < 104) v = g4[idx - 72];
                else if (idx < 212) v = q4[idx - 104];
                else                v = n4[idx - 212];
                d4[idx] = v;
            }
        }
    } else {
        for (int idx = l; idx < 864; idx += 64) {
            if (idx < 144)       { int i = idx / 9, j = idx % 9;              int f = min(f0 + i, NF - 1); sIn[idx] = bary[9 * (size_t)f + j]; }
            else if (idx < 288)  { int e = idx - 144; int i = e / 9,  j = e % 9;  int f = min(f0 + i, NF - 1); sIn[idx] = tex [9 * (size_t)f + j]; }
            else if (idx < 416)  { int e = idx - 288; int i = e / 8,  g = e % 8;  int f = min(f0 + i, NF - 1); sIn[idx] = geo [8 * (size_t)f + g]; }
            else if (idx < 848)  { int e = idx - 416; int i = e / 27, k = e % 27; int f = min(f0 + i, NF - 1); sIn[idx] = filt[27 * (size_t)f + k]; }
            else                 { int i = idx - 848;                              int f = min(f0 + i, NF - 1); ((int*)sIn)[idx] = numtex[f]; }
        }
    }

    const s16x8* wsF2f = wsAll;
    const s16x8* wsMlp = wsAll + 4 * 64;
    const s16x8* wsWdw = wsAll + 8 * 64;
    const s16x8* wsWpw = wsAll + 24 * 64;
    const f32x4 z4 = {0.f, 0.f, 0.f, 0.f};

    // ---- front end: A-frags + Tnet/Gnet from LDS inputs ----
    const int i = o16;
    const float* bp = sIn + i * 9;
    const float* tp = sIn + 144 + i * 9;
    float Bm[9] = {0.f,0.f,0.f,0.f,0.f,0.f,0.f,0.f,0.f};
#pragma unroll
    for (int t = 0; t < 3; ++t) {
        float b0 = bp[3*t], b1 = bp[3*t+1], b2 = bp[3*t+2];
        float x0 = tp[3*t], x1 = tp[3*t+1], x2 = tp[3*t+2];
        Bm[0] = fmaf(b0, x0, Bm[0]); Bm[1] = fmaf(b0, x1, Bm[1]); Bm[2] = fmaf(b0, x2, Bm[2]);
        Bm[3] = fmaf(b1, x0, Bm[3]); Bm[4] = fmaf(b1, x1, Bm[4]); Bm[5] = fmaf(b1, x2, Bm[5]);
        Bm[6] = fmaf(b2, x0, Bm[6]); Bm[7] = fmaf(b2, x1, Bm[7]); Bm[8] = fmaf(b2, x2, Bm[8]);
    }
    s16x8 aF2f;
    aF2f[0] = f2bf((k4 == 1) ? Bm[8] : Bm[0]);   // k4==1 lane supplies A[k=8]
#pragma unroll
    for (int j = 1; j < 8; ++j) aF2f[j] = f2bf(Bm[j]);

    const float* gp = sIn + 288 + i * 8;
    s16x8 aMlp;
#pragma unroll
    for (int j = 0; j < 8; ++j) aMlp[j] = f2bf(gp[j]);

    const float* fp = sIn + 416 + i * 27 + k4 * 8;
    s16x8 aFlt;
#pragma unroll
    for (int j = 0; j < 8; ++j) {
        int k = k4 * 8 + j;
        aFlt[j] = (k < 27) ? f2bf(fp[j]) : (short)0;
    }

    float invn[4];
#pragma unroll
    for (int t = 0; t < 4; ++t) invn[t] = 1.0f / (float)((const int*)sIn)[848 + 4 * k4 + t];
    float bfo[4], bmo[4];
#pragma unroll
    for (int nt = 0; nt < 4; ++nt) { bfo[nt] = bf2f[nt * 16 + o16]; bmo[nt] = bmlp[nt * 16 + o16]; }

    float tn[4][4], gn[4][4];                // [nt][t], D-layout row m=4*k4+t, col nt*16+o16
#pragma unroll
    for (int nt = 0; nt < 4; ++nt) {
        f32x4 aT = __builtin_amdgcn_mfma_f32_16x16x32_bf16(aF2f, wsF2f[nt * 64 + l], z4, 0, 0, 0);
        f32x4 aG = __builtin_amdgcn_mfma_f32_16x16x32_bf16(aMlp, wsMlp[nt * 64 + l], z4, 0, 0, 0);
#pragma unroll
        for (int t = 0; t < 4; ++t) {
            bool mv = (f0 + 4 * k4 + t) < NF;
            float tv = fmaxf(fmaf(aT[t], invn[t], bfo[nt]), 0.f);
            float gv = fmaxf(aG[t] + bmo[nt], 0.f);
            tn[nt][t] = mv ? tv : 0.f;
            gn[nt][t] = mv ? gv : 0.f;
        }
    }

    // ---- phase 2 / GEMM1: mk' = filt16 @ Wdw'; ct' = mk' * net (lane-local!) ----
    // Permuted column r' = nt2*16+o16 has ch = (nt2>>1)*16+o16 -> this lane's own
    // tn/gn register. No cross-lane ops.
#pragma unroll
    for (int nt2 = 0; nt2 < 16; ++nt2) {
        f32x4 acc = __builtin_amdgcn_mfma_f32_16x16x32_bf16(aFlt, wsWdw[nt2 * 64 + l], z4, 0, 0, 0);
        const int cblk = nt2 >> 1;
        const int r = nt2 * 16 + o16;
#pragma unroll
        for (int t = 0; t < 4; ++t) {
            float netv = (nt2 < 8) ? tn[cblk][t] : gn[cblk - 4][t];
            float cv = acc[t] * netv;
            const int m = 4 * k4 + t;
            *(short*)(sW + m * 512 + ((r * 2) ^ ((m & 7) << 4))) = f2bf(cv);
        }
    }

    // ---- GEMM2: y = ct' @ Wpw' ----
    f32x4 acc2[4] = {z4, z4, z4, z4};
#pragma unroll
    for (int kc = 0; kc < 8; ++kc) {
        s16x8 a2 = *(const s16x8*)(sW + o16 * 512 + ((kc * 64 + k4 * 16) ^ ((o16 & 7) << 4)));
#pragma unroll
        for (int nt = 0; nt < 4; ++nt)
            acc2[nt] = __builtin_amdgcn_mfma_f32_16x16x32_bf16(a2, wsWpw[(nt * 8 + kc) * 64 + l], acc2[nt], 0, 0, 0);
    }

    // ---- phase 3: y -> bf16 via LDS transpose, coalesced dwordx4 stores ----
#pragma unroll
    for (int nt = 0; nt < 4; ++nt)
#pragma unroll
        for (int t = 0; t < 4; ++t) {
            const int m = 4 * k4 + t;
            const int c = nt * 16 + o16;
            int off = m * 128 + c * 2;
            off ^= ((m & 7) << 4);
            *(short*)(sW + off) = f2bf(acc2[nt][t]);
        }
    {
        char* dst = (char*)(ybf) + (size_t)tile * 2048;   // [16][64] bf16
#pragma unroll
        for (int q = 0; q < 2; ++q) {
            const int L = (l + q * 64) * 16;
            const int m = L >> 7;
            s16x8 v = *(const s16x8*)(sW + (L ^ ((m & 7) << 4)));
            *(s16x8*)(dst + L) = v;
        }
    }
}

// ---------------- CSR gather: mean + bias + relu ----------------
// thread = (vertex, channel-pair); one u32 (2 bf16) per incidence.
__global__ __launch_bounds__(256) void vertex_kernel(
    const u32* __restrict__ y32, const int* __restrict__ vt_map,
    const int* __restrict__ startArr, const int* __restrict__ nfc,
    const float* __restrict__ bpw, float* __restrict__ out, int NV)
{
    const int tid = blockIdx.x * 256 + threadIdx.x;
    const int v  = tid >> 5;
    const int c2 = tid & 31;
    if (v >= NV) return;
    const int start = startArr[v];
    const int cnt   = nfc[v];
    float aLo = 0.f, aHi = 0.f;
    int i = 0;
    for (; i + 4 <= cnt; i += 4) {
        const int fa = vt_map[start + i];
        const int fb = vt_map[start + i + 1];
        const int fc = vt_map[start + i + 2];
        const int fd = vt_map[start + i + 3];
        u32 wa = y32[(size_t)fa * 32 + c2];
        u32 wb = y32[(size_t)fb * 32 + c2];
        u32 wc = y32[(size_t)fc * 32 + c2];
        u32 wd = y32[(size_t)fd * 32 + c2];
        union { u32 u; float f; } x;
        x.u = wa << 16; aLo += x.f;  x.u = wa & 0xffff0000u; aHi += x.f;
        x.u = wb << 16; aLo += x.f;  x.u = wb & 0xffff0000u; aHi += x.f;
        x.u = wc << 16; aLo += x.f;  x.u = wc & 0xffff0000u; aHi += x.f;
        x.u = wd << 16; aLo += x.f;  x.u = wd & 0xffff0000u; aHi += x.f;
    }
    for (; i < cnt; ++i) {
        u32 w = y32[(size_t)vt_map[start + i] * 32 + c2];
        union { u32 u; float f; } x;
        x.u = w << 16; aLo += x.f;  x.u = w & 0xffff0000u; aHi += x.f;
    }
    const float inv = 1.0f / (float)(cnt > 0 ? cnt : 1);
    float2 r;
    r.x = fmaxf(fmaf(aLo, inv, bpw[2 * c2]), 0.f);
    r.y = fmaxf(fmaf(aHi, inv, bpw[2 * c2 + 1]), 0.f);
    *(float2*)(out + (size_t)v * 64 + 2 * c2) = r;
}

extern "C" void kernel_launch(void* const* d_in, const int* in_sizes, int n_in,
                              void* d_out, int out_size, void* d_ws, size_t ws_size,
                              hipStream_t stream)
{
    const float* geo    = (const float*)d_in[0];   // [NF,8]
    const float* tex    = (const float*)d_in[1];   // [T,3]
    const float* bary   = (const float*)d_in[2];   // [T,3]
    const int*   numtex = (const int*)  d_in[3];   // [NF]
    const int*   nfc    = (const int*)  d_in[5];   // [NV]
    const int*   vtmap  = (const int*)  d_in[6];   // [3*NF]
    const float* filt   = (const float*)d_in[7];   // [NF,27]
    const float* Wf2f   = (const float*)d_in[8];   // [9,64]
    const float* bf2f   = (const float*)d_in[9];   // [64]
    const float* Wmlp   = (const float*)d_in[10];  // [8,64]
    const float* bmlp   = (const float*)d_in[11];  // [64]
    const float* Wdw    = (const float*)d_in[12];  // [27,128,2]
    const float* Wpw    = (const float*)d_in[13];  // [256,64]
    const float* bpw    = (const float*)d_in[14];  // [64]
    float* out = (float*)d_out;

    const int NF = in_sizes[0] / 8;
    const int NV = in_sizes[5];
    const int ntiles = (NF + 15) / 16;
    const int NB = (NV + 511) / 512;               // <=256 for NV<=131072

    // ws layout
    const size_t offFrag  = 0;                                   // 57344 B
    const size_t offY     = 57344;                               // ntiles*2048 B (bf16 y)
    const size_t offStart = offY + (size_t)ntiles * 2048;
    const size_t offBsum  = offStart + (((size_t)NV * 4 + 255) & ~(size_t)255);
    const size_t offBoff  = offBsum + 1024;

    s16x8*          wsAll    = (s16x8*)((char*)d_ws + offFrag);
    unsigned short* ybf      = (unsigned short*)((char*)d_ws + offY);
    int*            startArr = (int*)((char*)d_ws + offStart);
    int*            bsum     = (int*)((char*)d_ws + offBsum);
    int*            boff     = (int*)((char*)d_ws + offBoff);

    hipLaunchKernelGGL(prep_kernel, dim3(14), dim3(256), 0, stream,
                       Wf2f, Wmlp, Wdw, Wpw, wsAll);
    hipLaunchKernelGGL(scanA, dim3(NB), dim3(256), 0, stream, nfc, bsum, NV);
    hipLaunchKernelGGL(scanB, dim3(1),  dim3(256), 0, stream, bsum, boff, NB);
    hipLaunchKernelGGL(scanC, dim3(NB), dim3(256), 0, stream, nfc, boff, startArr, NV);

    hipLaunchKernelGGL(facet_kernel, dim3((ntiles + 3) / 4), dim3(256), 0, stream,
                       geo, tex, bary, numtex, filt, bf2f, bmlp, wsAll, ybf, NF, ntiles);

    const int vthreads = NV * 32;
    hipLaunchKernelGGL(vertex_kernel, dim3((vthreads + 255) / 256), dim3(256), 0, stream,
                       (const u32*)ybf, vtmap, startArr, nfc, bpw, out, NV);
}